// Round 3
// baseline (234.057 us; speedup 1.0000x reference)
//
#include <hip/hip_runtime.h>

#define SEQ 64
#define D 28
#define EMB 784  // 28*28
#define CH 8     // leaf chain length per chain

typedef float float4v __attribute__((ext_vector_type(4)));

// Publish C^T (from 4x4 register tile of C) into this chain's LDS region.
__device__ __forceinline__ void xpose_write(const float4v ct[4],
                                            float* __restrict__ LTw,
                                            int it, int jt)
{
#pragma unroll
    for (int c = 0; c < 4; ++c) {
        float4v t;
        t.x = ct[0][c]; t.y = ct[1][c]; t.z = ct[2][c]; t.w = ct[3][c];
        *(float4v*)&LTw[(4 * jt + c) * D + 4 * it] = t;
    }
}

// One chain step for TWO independent chains interleaved (ILP hides the
// LDS round-trip + global B-load latency of each other).
//   C_new = C * B ; rank-1 over k: acc[r][c] += C^T[k][4it+r] * B[k][4jt+c]
__device__ __forceinline__ void step2(float4v ct0[4], float4v ct1[4],
                                      const float* __restrict__ rowB0,
                                      const float* __restrict__ rowB1,
                                      float* __restrict__ LT0,
                                      float* __restrict__ LT1,
                                      int it, int jt)
{
    xpose_write(ct0, LT0, it, jt);
    xpose_write(ct1, LT1, it, jt);
    __builtin_amdgcn_s_waitcnt(0xC07F);  // lgkmcnt(0): transposes visible

    const float* bp0 = rowB0 + 4 * jt;
    const float* bp1 = rowB1 + 4 * jt;
    const float* ap0 = LT0 + 4 * it;
    const float* ap1 = LT1 + 4 * it;

    float4v acc0[4] = {};
    float4v acc1[4] = {};
#pragma unroll
    for (int g = 0; g < 7; ++g) {
        float4v b0[4], b1[4], a0[4], a1[4];
#pragma unroll
        for (int q = 0; q < 4; ++q) {
            const int k = 4 * g + q;
            b0[q] = *(const float4v*)(bp0 + k * D);
            b1[q] = *(const float4v*)(bp1 + k * D);
            a0[q] = *(const float4v*)(ap0 + k * D);
            a1[q] = *(const float4v*)(ap1 + k * D);
        }
#pragma unroll
        for (int q = 0; q < 4; ++q) {
#pragma unroll
            for (int r = 0; r < 4; ++r) {
                acc0[r] += b0[q] * a0[q][r];
                acc1[r] += b1[q] * a1[q][r];
            }
        }
    }
#pragma unroll
    for (int r = 0; r < 4; ++r) { ct0[r] = acc0[r]; ct1[r] = acc1[r]; }
}

// Leaf: wave w handles chains (b, gp) and (b, gp+1): products of words
// 8*gp..8*gp+7 and 8*(gp+1)..  4096 waves total.
__global__ __launch_bounds__(256, 4) void w2m_leaf(
    const int* __restrict__ sent,
    const float* __restrict__ table,
    float* __restrict__ ws0)
{
    __shared__ float LT[8 * EMB] __attribute__((aligned(16)));  // 2 regions x 4 waves
    const int lane = threadIdx.x & 63;
    const int wid  = threadIdx.x >> 6;
    const int w = blockIdx.x * 4 + wid;     // 0..4095
    const int b = w >> 2;
    const int gp = (w & 3) * 2;             // 0,2,4,6
    int it = lane / 7, jt = lane % 7;
    const bool act = lane < 49;
    if (!act) { it = 6; jt = 6; }
    float* LT0 = &LT[(wid * 2 + 0) * EMB];
    float* LT1 = &LT[(wid * 2 + 1) * EMB];

    const int idxA = sent[b * SEQ + 8 * gp + (lane & 7)];
    const int idxB = sent[b * SEQ + 8 * (gp + 1) + (lane & 7)];

    // wave-uniform word indices -> SGPRs (all lanes participate, exec-safe)
    int ja[CH], jb[CH];
#pragma unroll
    for (int j = 0; j < CH; ++j) {
        ja[j] = __builtin_amdgcn_readlane(idxA, j);
        jb[j] = __builtin_amdgcn_readlane(idxB, j);
    }

    if (act) {
        const float* r0 = table + (size_t)ja[0] * EMB;
        const float* r1 = table + (size_t)jb[0] * EMB;
        float4v ct0[4], ct1[4];
#pragma unroll
        for (int r = 0; r < 4; ++r) {
            ct0[r] = *(const float4v*)(r0 + (4 * it + r) * D + 4 * jt);
            ct1[r] = *(const float4v*)(r1 + (4 * it + r) * D + 4 * jt);
        }

#pragma unroll 1
        for (int j = 1; j < CH; ++j) {
            step2(ct0, ct1,
                  table + (size_t)ja[j] * EMB,
                  table + (size_t)jb[j] * EMB,
                  LT0, LT1, it, jt);
        }

        float* o0 = ws0 + (size_t)(b * 8 + gp) * EMB;
        float* o1 = ws0 + (size_t)(b * 8 + gp + 1) * EMB;
#pragma unroll
        for (int r = 0; r < 4; ++r) {
            *(float4v*)(o0 + (4 * it + r) * D + 4 * jt) = ct0[r];
            *(float4v*)(o1 + (4 * it + r) * D + 4 * jt) = ct1[r];
        }
    }
}

// Top: one wave per block handles sentences 2u and 2u+1 (8 partials each).
__global__ __launch_bounds__(64) void w2m_top(
    const float* __restrict__ ws0,
    float* __restrict__ out)
{
    __shared__ float LT[2 * EMB] __attribute__((aligned(16)));
    const int lane = threadIdx.x;
    const int b0 = blockIdx.x * 2;
    const int b1 = b0 + 1;
    int it = lane / 7, jt = lane % 7;
    const bool act = lane < 49;
    if (!act) { it = 6; jt = 6; }

    if (act) {
        const float* base0 = ws0 + (size_t)b0 * CH * EMB;
        const float* base1 = ws0 + (size_t)b1 * CH * EMB;
        float4v ct0[4], ct1[4];
#pragma unroll
        for (int r = 0; r < 4; ++r) {
            ct0[r] = *(const float4v*)(base0 + (4 * it + r) * D + 4 * jt);
            ct1[r] = *(const float4v*)(base1 + (4 * it + r) * D + 4 * jt);
        }
#pragma unroll 1
        for (int j = 1; j < CH; ++j) {
            step2(ct0, ct1,
                  base0 + (size_t)j * EMB,
                  base1 + (size_t)j * EMB,
                  &LT[0], &LT[EMB], it, jt);
        }
        float* o0 = out + (size_t)b0 * EMB;
        float* o1 = out + (size_t)b1 * EMB;
#pragma unroll
        for (int r = 0; r < 4; ++r) {
            *(float4v*)(o0 + (4 * it + r) * D + 4 * jt) = ct0[r];
            *(float4v*)(o1 + (4 * it + r) * D + 4 * jt) = ct1[r];
        }
    }
}

// ---- Fallback: single-kernel serial scan (used only if ws too small) ----
__device__ __forceinline__ void chain_step1(float4v ct[4],
                                            const float* __restrict__ rowB,
                                            float* __restrict__ LTw,
                                            int it, int jt)
{
    xpose_write(ct, LTw, it, jt);
    __builtin_amdgcn_s_waitcnt(0xC07F);
    const float* bp = rowB + 4 * jt;
    const float* ap = LTw + 4 * it;
    float4v acc[4] = {};
#pragma unroll
    for (int g = 0; g < 7; ++g) {
        float4v bb[4], aa[4];
#pragma unroll
        for (int q = 0; q < 4; ++q) {
            const int k = 4 * g + q;
            bb[q] = *(const float4v*)(bp + k * D);
            aa[q] = *(const float4v*)(ap + k * D);
        }
#pragma unroll
        for (int q = 0; q < 4; ++q)
#pragma unroll
            for (int r = 0; r < 4; ++r) acc[r] += bb[q] * aa[q][r];
    }
#pragma unroll
    for (int r = 0; r < 4; ++r) ct[r] = acc[r];
}

__global__ __launch_bounds__(64) void w2m_serial(
    const int* __restrict__ sent,
    const float* __restrict__ table,
    float* __restrict__ out)
{
    __shared__ float LT[EMB] __attribute__((aligned(16)));
    const int lane = threadIdx.x;
    const int b = blockIdx.x;
    int it = lane / 7, jt = lane % 7;
    const bool act = (lane < 49);
    if (!act) { it = 6; jt = 6; }
    const int myidx = sent[b * SEQ + lane];
    int jl[SEQ];
#pragma unroll
    for (int s = 0; s < SEQ; ++s) jl[s] = __builtin_amdgcn_readlane(myidx, s);
    if (act) {
        const float* row0 = table + (size_t)jl[0] * EMB;
        float4v ct[4];
#pragma unroll
        for (int r = 0; r < 4; ++r)
            ct[r] = *(const float4v*)(row0 + (4 * it + r) * D + 4 * jt);
#pragma unroll 1
        for (int s = 1; s < SEQ; ++s)
            chain_step1(ct, table + (size_t)jl[s] * EMB, LT, it, jt);
        float* orow = out + (size_t)b * EMB;
#pragma unroll
        for (int r = 0; r < 4; ++r)
            *(float4v*)(orow + (4 * it + r) * D + 4 * jt) = ct[r];
    }
}

extern "C" void kernel_launch(void* const* d_in, const int* in_sizes, int n_in,
                              void* d_out, int out_size, void* d_ws, size_t ws_size,
                              hipStream_t stream) {
    const int* sent = (const int*)d_in[0];
    const float* table = (const float*)d_in[1];
    float* out = (float*)d_out;
    const int batch = in_sizes[0] / SEQ;                  // 1024
    const size_t ws_needed = (size_t)batch * CH * EMB * sizeof(float);  // 25.7 MB

    if (ws_size >= ws_needed) {
        float* ws0 = (float*)d_ws;
        const int waves1 = batch * CH / 2;                // 4096 leaf waves
        hipLaunchKernelGGL(w2m_leaf, dim3(waves1 / 4), dim3(256), 0, stream,
                           sent, table, ws0);
        hipLaunchKernelGGL(w2m_top, dim3(batch / 2), dim3(64), 0, stream,
                           ws0, out);
    } else {
        hipLaunchKernelGGL(w2m_serial, dim3(batch), dim3(64), 0, stream,
                           sent, table, out);
    }
}

// Round 4
// 200.038 us; speedup vs baseline: 1.1701x; 1.1701x over previous
//
#include <hip/hip_runtime.h>

#define SEQ 64
#define D 28
#define EMB 784  // 28*28
#define CH 8     // leaf chain length

typedef float float4v __attribute__((ext_vector_type(4)));

// Publish C^T (from the 4x4 register tile of C) into this wave's LDS region.
__device__ __forceinline__ void xpose_write(const float4v ct[4],
                                            float* __restrict__ LTw,
                                            int it, int jt)
{
#pragma unroll
    for (int c = 0; c < 4; ++c) {
        float4v t;
        t.x = ct[0][c]; t.y = ct[1][c]; t.z = ct[2][c]; t.w = ct[3][c];
        *(float4v*)&LTw[(4 * jt + c) * D + 4 * it] = t;
    }
}

// Software-pipelined chain: ct <- ct * rows[1] * rows[2] * ... * rows[CNT-1].
// P[28] holds the NEXT step's full B row in registers; P[k] is refilled
// right after its last use, giving every global load 200-1100 cyc of lead.
// rowptr(j) must return the (wave-uniform) pointer to row j.
template <int CNT, typename F>
__device__ __forceinline__ void mat_chain(F rowptr, float* __restrict__ LTw,
                                          float4v ct[4], int it, int jt)
{
    const float* bp = rowptr(1) + 4 * jt;
    float4v P[28];
#pragma unroll
    for (int k = 0; k < 28; ++k) P[k] = *(const float4v*)(bp + k * D);

#pragma unroll 1
    for (int j = 1; j < CNT; ++j) {
        xpose_write(ct, LTw, it, jt);
        __builtin_amdgcn_s_waitcnt(0xC07F);  // lgkmcnt(0): transpose visible

        // next row to prefetch; on the final step re-point at the row we are
        // consuming right now (L1-hot -> dummy refill is nearly free).
        const float* np = rowptr(j + 1 < CNT ? j + 1 : j) + 4 * jt;
        const float* ap = LTw + 4 * it;

        float4v acc[4] = {};
#pragma unroll
        for (int k = 0; k < 28; ++k) {
            float4v av = *(const float4v*)(ap + k * D);  // A slice C^T[k][4it..]
            float4v bb = P[k];
            P[k] = *(const float4v*)(np + k * D);        // refill for step j+1
#pragma unroll
            for (int r = 0; r < 4; ++r) acc[r] += bb * av[r];
        }
#pragma unroll
        for (int r = 0; r < 4; ++r) ct[r] = acc[r];
    }
}

// Leaf: wave w = (sentence b, group g) computes product of words 8g..8g+7.
__global__ __launch_bounds__(256, 1) void w2m_leaf(
    const int* __restrict__ sent,
    const float* __restrict__ table,
    float* __restrict__ ws0)
{
    __shared__ float LT[4 * EMB] __attribute__((aligned(16)));
    const int lane = threadIdx.x & 63;
    const int wid  = threadIdx.x >> 6;
    const int w = blockIdx.x * 4 + wid;   // 0..8191
    const int b = w >> 3;
    const int g = w & 7;
    const int it = lane / 7, jt = lane % 7;
    float* LTw = &LT[wid * EMB];

    const int myidx = sent[b * SEQ + 8 * g + (lane & 7)];
    int jl[CH];
#pragma unroll
    for (int j = 0; j < CH; ++j) jl[j] = __builtin_amdgcn_readlane(myidx, j);

    if (lane >= 49) return;  // wave-private LDS, no barriers -> safe to retire

    const float* row0 = table + (size_t)jl[0] * EMB;
    float4v ct[4];
#pragma unroll
    for (int r = 0; r < 4; ++r)
        ct[r] = *(const float4v*)(row0 + (4 * it + r) * D + 4 * jt);

    mat_chain<CH>([&](int j) { return table + (size_t)jl[j] * EMB; },
                  LTw, ct, it, jt);

    float* orow = ws0 + (size_t)w * EMB;
#pragma unroll
    for (int r = 0; r < 4; ++r)
        *(float4v*)(orow + (4 * it + r) * D + 4 * jt) = ct[r];
}

// Top: wave b multiplies the 8 partial products of sentence b -> d_out.
__global__ __launch_bounds__(64, 1) void w2m_top(
    const float* __restrict__ ws0,
    float* __restrict__ out)
{
    __shared__ float LT[EMB] __attribute__((aligned(16)));
    const int lane = threadIdx.x;
    const int b = blockIdx.x;
    const int it = lane / 7, jt = lane % 7;
    if (lane >= 49) return;

    const float* base = ws0 + (size_t)b * CH * EMB;
    float4v ct[4];
#pragma unroll
    for (int r = 0; r < 4; ++r)
        ct[r] = *(const float4v*)(base + (4 * it + r) * D + 4 * jt);

    mat_chain<CH>([&](int j) { return base + (size_t)j * EMB; },
                  LT, ct, it, jt);

    float* orow = out + (size_t)b * EMB;
#pragma unroll
    for (int r = 0; r < 4; ++r)
        *(float4v*)(orow + (4 * it + r) * D + 4 * jt) = ct[r];
}

// ---- Fallback: single-kernel serial scan (used only if ws too small) ----
__global__ __launch_bounds__(64, 1) void w2m_serial(
    const int* __restrict__ sent,
    const float* __restrict__ table,
    float* __restrict__ out)
{
    __shared__ float LT[EMB] __attribute__((aligned(16)));
    const int lane = threadIdx.x;
    const int b = blockIdx.x;
    const int it = lane / 7, jt = lane % 7;

    const int myidx = sent[b * SEQ + lane];
    int jl[SEQ];
#pragma unroll
    for (int s = 0; s < SEQ; ++s) jl[s] = __builtin_amdgcn_readlane(myidx, s);

    if (lane >= 49) return;

    const float* row0 = table + (size_t)jl[0] * EMB;
    float4v ct[4];
#pragma unroll
    for (int r = 0; r < 4; ++r)
        ct[r] = *(const float4v*)(row0 + (4 * it + r) * D + 4 * jt);

    mat_chain<SEQ>([&](int s) { return table + (size_t)jl[s] * EMB; },
                   LT, ct, it, jt);

    float* orow = out + (size_t)b * EMB;
#pragma unroll
    for (int r = 0; r < 4; ++r)
        *(float4v*)(orow + (4 * it + r) * D + 4 * jt) = ct[r];
}

extern "C" void kernel_launch(void* const* d_in, const int* in_sizes, int n_in,
                              void* d_out, int out_size, void* d_ws, size_t ws_size,
                              hipStream_t stream) {
    const int* sent = (const int*)d_in[0];
    const float* table = (const float*)d_in[1];
    float* out = (float*)d_out;
    const int batch = in_sizes[0] / SEQ;                  // 1024
    const size_t ws_needed = (size_t)batch * CH * EMB * sizeof(float);  // 25.7 MB

    if (ws_size >= ws_needed) {
        float* ws0 = (float*)d_ws;
        const int waves1 = batch * CH;                    // 8192 leaf waves
        hipLaunchKernelGGL(w2m_leaf, dim3(waves1 / 4), dim3(256), 0, stream,
                           sent, table, ws0);
        hipLaunchKernelGGL(w2m_top, dim3(batch), dim3(64), 0, stream,
                           ws0, out);
    } else {
        hipLaunchKernelGGL(w2m_serial, dim3(batch), dim3(64), 0, stream,
                           sent, table, out);
    }
}

// Round 5
// 179.959 us; speedup vs baseline: 1.3006x; 1.1116x over previous
//
#include <hip/hip_runtime.h>
#include <stdint.h>

#define SEQ 64
#define D 28
#define EMB 784   // 28*28
#define CH 8      // leaf chain length
#define BUFF 832  // LDS B-buffer floats: 3328 B = 3*1024 + 256 (DMA coverage)

typedef float float4v __attribute__((ext_vector_type(4)));

// ---- async global->LDS DMA of one 3136 B table row (+192 B tail overread).
// global_load_lds semantics: wave-uniform LDS base + lane*size. Row is
// contiguous row-major, so 3x(64 lanes x 16 B) + 1x(64 lanes x 4 B) = 3328 B.
// The 192 B overread past the row stays inside the (page-granular) table
// allocation and lands in LDS[3136..3328) which is never read.
__device__ __forceinline__ void dma_row(const float* grow, float* lbuf, int lane)
{
    const char* g16 = (const char*)grow + lane * 16;
    const char* g4  = (const char*)grow + 3072 + lane * 4;
    char* l = (char*)lbuf;
    __builtin_amdgcn_global_load_lds((const __attribute__((address_space(1))) void*)(g16),
                                     (__attribute__((address_space(3))) void*)(l), 16, 0, 0);
    __builtin_amdgcn_global_load_lds((const __attribute__((address_space(1))) void*)(g16 + 1024),
                                     (__attribute__((address_space(3))) void*)(l + 1024), 16, 0, 0);
    __builtin_amdgcn_global_load_lds((const __attribute__((address_space(1))) void*)(g16 + 2048),
                                     (__attribute__((address_space(3))) void*)(l + 2048), 16, 0, 0);
    __builtin_amdgcn_global_load_lds((const __attribute__((address_space(1))) void*)(g4),
                                     (__attribute__((address_space(3))) void*)(l + 3072), 4, 0, 0);
}

// Publish C^T (from the 4x4 register tile of C) into this wave's LDS region.
// Lanes 49..63 are clamped to (it,jt)=(6,6) and compute values identical to
// lane 48, so their same-address writes are benign (same data).
__device__ __forceinline__ void xpose_write(const float4v ct[4],
                                            float* __restrict__ LTw,
                                            int it, int jt)
{
#pragma unroll
    for (int c = 0; c < 4; ++c) {
        float4v t;
        t.x = ct[0][c]; t.y = ct[1][c]; t.z = ct[2][c]; t.w = ct[3][c];
        *(float4v*)&LTw[(4 * jt + c) * D + 4 * it] = t;
    }
}

// Chain ct <- ct * rows[1] * ... * rows[CNT-1], with the NEXT row DMA'd into
// the alternate LDS buffer one full step ahead (vmcnt(4) gate keeps exactly
// the 4 in-flight prefetch DMAs outstanding across the wait).
template <int CNT, typename F>
__device__ __forceinline__ void mat_chain(F rowptr, float* __restrict__ LTw,
                                          float* __restrict__ B0,
                                          float* __restrict__ B1,
                                          float4v ct[4], int it, int jt, int lane)
{
    dma_row(rowptr(1), B1, lane);  // row j lives in ((j&1) ? B1 : B0)

#pragma unroll 1
    for (int j = 1; j < CNT; ++j) {
        const int jn = (j + 1 < CNT) ? (j + 1) : j;  // clamped prefetch row
        float* nB = (j & 1) ? B0 : B1;               // target = other buffer
        float* cB = (j & 1) ? B1 : B0;
        dma_row(rowptr(jn), nB, lane);

        xpose_write(ct, LTw, it, jt);

        // Wait: row-j DMA + C^T transpose visible; row-(j+1) DMA (the 4
        // newest vmem ops) stays in flight. sched_barrier pins the ds_reads
        // below from being hoisted above the wait.
        __builtin_amdgcn_sched_barrier(0);
        __builtin_amdgcn_s_waitcnt(0x0074);  // vmcnt(4) lgkmcnt(0) expcnt(7)
        __builtin_amdgcn_sched_barrier(0);

        const float* ap = LTw + 4 * it;
        const float* bp = cB + 4 * jt;
        float4v acc[4] = {};
#pragma unroll
        for (int k = 0; k < 28; ++k) {
            float4v av = *(const float4v*)(ap + k * D);  // A slice C^T[k][4it..]
            float4v bb = *(const float4v*)(bp + k * D);  // B slice B[k][4jt..]
#pragma unroll
            for (int r = 0; r < 4; ++r) acc[r] += bb * av[r];
        }
#pragma unroll
        for (int r = 0; r < 4; ++r) ct[r] = acc[r];
    }
}

// Leaf: wave w = (sentence b, group g) computes product of words 8g..8g+7.
__global__ __launch_bounds__(256, 1) void w2m_leaf(
    const int* __restrict__ sent,
    const float* __restrict__ table,
    float* __restrict__ ws0)
{
    __shared__ float LT[4 * EMB] __attribute__((aligned(16)));
    __shared__ float BB[4 * 2 * BUFF] __attribute__((aligned(16)));
    const int lane = threadIdx.x & 63;
    const int wid  = threadIdx.x >> 6;
    const int w = blockIdx.x * 4 + wid;   // 0..8191
    const int b = w >> 3;
    const int g = w & 7;
    int it = lane / 7, jt = lane % 7;
    const bool act = lane < 49;
    if (!act) { it = 6; jt = 6; }  // lanes 49+ mirror lane 48 (same data)
    float* LTw = &LT[wid * EMB];
    float* Bw0 = &BB[wid * 2 * BUFF];
    float* Bw1 = Bw0 + BUFF;

    const int myidx = sent[b * SEQ + 8 * g + (lane & 7)];
    int jl[CH];
#pragma unroll
    for (int j = 0; j < CH; ++j) jl[j] = __builtin_amdgcn_readlane(myidx, j);

    const float* row0 = table + (size_t)jl[0] * EMB;
    float4v ct[4];
#pragma unroll
    for (int r = 0; r < 4; ++r)
        ct[r] = *(const float4v*)(row0 + (4 * it + r) * D + 4 * jt);

    mat_chain<CH>([&](int j) { return table + (size_t)jl[j] * EMB; },
                  LTw, Bw0, Bw1, ct, it, jt, lane);

    if (act) {
        float* orow = ws0 + (size_t)w * EMB;
#pragma unroll
        for (int r = 0; r < 4; ++r)
            *(float4v*)(orow + (4 * it + r) * D + 4 * jt) = ct[r];
    }
}

// Top: wave b multiplies the 8 partial products of sentence b -> d_out.
__global__ __launch_bounds__(64, 1) void w2m_top(
    const float* __restrict__ ws0,
    float* __restrict__ out)
{
    __shared__ float LT[EMB] __attribute__((aligned(16)));
    __shared__ float BB[2 * BUFF] __attribute__((aligned(16)));
    const int lane = threadIdx.x;
    const int b = blockIdx.x;
    int it = lane / 7, jt = lane % 7;
    const bool act = lane < 49;
    if (!act) { it = 6; jt = 6; }

    const float* base = ws0 + (size_t)b * CH * EMB;
    float4v ct[4];
#pragma unroll
    for (int r = 0; r < 4; ++r)
        ct[r] = *(const float4v*)(base + (4 * it + r) * D + 4 * jt);

    mat_chain<CH>([&](int j) { return base + (size_t)j * EMB; },
                  LT, &BB[0], &BB[BUFF], ct, it, jt, lane);

    if (act) {
        float* orow = out + (size_t)b * EMB;
#pragma unroll
        for (int r = 0; r < 4; ++r)
            *(float4v*)(orow + (4 * it + r) * D + 4 * jt) = ct[r];
    }
}

// ---- Fallback: single-kernel serial scan (used only if ws too small) ----
__global__ __launch_bounds__(64, 1) void w2m_serial(
    const int* __restrict__ sent,
    const float* __restrict__ table,
    float* __restrict__ out)
{
    __shared__ float LT[EMB] __attribute__((aligned(16)));
    __shared__ float BB[2 * BUFF] __attribute__((aligned(16)));
    const int lane = threadIdx.x;
    const int b = blockIdx.x;
    int it = lane / 7, jt = lane % 7;
    const bool act = lane < 49;
    if (!act) { it = 6; jt = 6; }

    const int myidx = sent[b * SEQ + lane];
    int jl[SEQ];
#pragma unroll
    for (int s = 0; s < SEQ; ++s) jl[s] = __builtin_amdgcn_readlane(myidx, s);

    const float* row0 = table + (size_t)jl[0] * EMB;
    float4v ct[4];
#pragma unroll
    for (int r = 0; r < 4; ++r)
        ct[r] = *(const float4v*)(row0 + (4 * it + r) * D + 4 * jt);

    mat_chain<SEQ>([&](int s) { return table + (size_t)jl[s] * EMB; },
                   LT, &BB[0], &BB[BUFF], ct, it, jt, lane);

    if (act) {
        float* orow = out + (size_t)b * EMB;
#pragma unroll
        for (int r = 0; r < 4; ++r)
            *(float4v*)(orow + (4 * it + r) * D + 4 * jt) = ct[r];
    }
}

extern "C" void kernel_launch(void* const* d_in, const int* in_sizes, int n_in,
                              void* d_out, int out_size, void* d_ws, size_t ws_size,
                              hipStream_t stream) {
    const int* sent = (const int*)d_in[0];
    const float* table = (const float*)d_in[1];
    float* out = (float*)d_out;
    const int batch = in_sizes[0] / SEQ;                  // 1024
    const size_t ws_needed = (size_t)batch * CH * EMB * sizeof(float);  // 25.7 MB

    if (ws_size >= ws_needed) {
        float* ws0 = (float*)d_ws;
        const int waves1 = batch * CH;                    // 8192 leaf waves
        hipLaunchKernelGGL(w2m_leaf, dim3(waves1 / 4), dim3(256), 0, stream,
                           sent, table, ws0);
        hipLaunchKernelGGL(w2m_top, dim3(batch), dim3(64), 0, stream,
                           ws0, out);
    } else {
        hipLaunchKernelGGL(w2m_serial, dim3(batch), dim3(64), 0, stream,
                           sent, table, out);
    }
}

// Round 6
// 169.742 us; speedup vs baseline: 1.3789x; 1.0602x over previous
//
#include <hip/hip_runtime.h>
#include <stdint.h>

#define SEQ 64
#define D 28
#define EMB 784   // 28*28
#define CH 8      // leaf chain length
#define BUFF 832  // fp32-path LDS B-buffer floats (3328 B DMA coverage)
#define BUFW 1024 // mfma-path B buffer floats (4 KB; DMA writes first 3328 B)
#define CTW 36    // CT row stride in floats (bank-decorrelating, 16B-align ok)
#define CTSZ (32 * CTW)  // 1152 floats per wave

typedef float float4v __attribute__((ext_vector_type(4)));
typedef __bf16 bf16x8 __attribute__((ext_vector_type(8)));

union FragU { unsigned u[4]; bf16x8 v; };

__device__ __forceinline__ unsigned fbits(float x) { union { float f; unsigned u; } t; t.f = x; return t.u; }
__device__ __forceinline__ float fof(unsigned u) { union { unsigned u; float f; } t; t.u = u; return t.f; }

// Split 8 fp32 (k-order) into hi/lo bf16 fragments (truncation split:
// x = hi + lo + O(2^-16 |x|); MFMA computes hi*hi + hi*lo + lo*hi).
__device__ __forceinline__ void split_frags(const float x[8], bf16x8& hi, bf16x8& lo)
{
    FragU H, L;
#pragma unroll
    for (int p = 0; p < 4; ++p) {
        unsigned ua = fbits(x[2 * p]), ub = fbits(x[2 * p + 1]);
        H.u[p] = (ua >> 16) | (ub & 0xFFFF0000u);
        unsigned la = fbits(x[2 * p]     - fof(ua & 0xFFFF0000u));
        unsigned lb = fbits(x[2 * p + 1] - fof(ub & 0xFFFF0000u));
        L.u[p] = (la >> 16) | (lb & 0xFFFF0000u);
    }
    hi = H.v; lo = L.v;
}

// ---- async global->LDS DMA of one 3136 B table row (+192 B tail overread).
__device__ __forceinline__ void dma_row(const float* grow, float* lbuf, int lane)
{
    const char* g16 = (const char*)grow + lane * 16;
    const char* g4  = (const char*)grow + 3072 + lane * 4;
    char* l = (char*)lbuf;
    __builtin_amdgcn_global_load_lds((const __attribute__((address_space(1))) void*)(g16),
                                     (__attribute__((address_space(3))) void*)(l), 16, 0, 0);
    __builtin_amdgcn_global_load_lds((const __attribute__((address_space(1))) void*)(g16 + 1024),
                                     (__attribute__((address_space(3))) void*)(l + 1024), 16, 0, 0);
    __builtin_amdgcn_global_load_lds((const __attribute__((address_space(1))) void*)(g16 + 2048),
                                     (__attribute__((address_space(3))) void*)(l + 2048), 16, 0, 0);
    __builtin_amdgcn_global_load_lds((const __attribute__((address_space(1))) void*)(g4),
                                     (__attribute__((address_space(3))) void*)(l + 3072), 4, 0, 0);
}

// ================= MFMA leaf =================
// Wave w = (sentence b, group g): product of words 8g..8g+7 as 32x32-padded
// bf16 hi/lo MFMA chain. State C lives in 2x2 16x16 D-frags
// (C/D layout: col=lane&15, row=(lane>>4)*4+reg  [m89/m91 verified]).
// Per step: publish C row-major to CT (stride 36), rebuild A-frags
// (A[m=lane&15+16R][k=(lane>>4)*8+j]) from CT, B-frags from the DMA'd
// fp32 row (stride 28), 12 MFMAs. k>=28 zeroed in registers; pad rows/cols
// carry garbage that only ever flows to pad rows/cols.
__global__ __launch_bounds__(256, 1) void w2m_leaf_mfma(
    const int* __restrict__ sent,
    const float* __restrict__ table,
    float* __restrict__ ws0)
{
    __shared__ float CT[4 * CTSZ] __attribute__((aligned(16)));
    __shared__ float BB[4 * 2 * BUFW] __attribute__((aligned(16)));
    const int lane = threadIdx.x & 63;
    const int wid  = threadIdx.x >> 6;
    const int w = blockIdx.x * 4 + wid;   // 0..8191
    const int b = w >> 3;
    const int g = w & 7;
    const int c = lane & 15;
    const int quad = lane >> 4;
    const bool q3 = (quad == 3);
    float* CTw = &CT[wid * CTSZ];
    float* B0 = &BB[wid * 2 * BUFW];
    float* B1 = B0 + BUFW;

    const int myidx = sent[b * SEQ + 8 * g + (lane & 7)];
    int jl[CH];
#pragma unroll
    for (int j = 0; j < CH; ++j) jl[j] = __builtin_amdgcn_readlane(myidx, j);

    dma_row(table + (size_t)jl[0] * EMB, B0, lane);
    dma_row(table + (size_t)jl[1] * EMB, B1, lane);
    __builtin_amdgcn_s_waitcnt(0x0074);  // vmcnt(4): row0 landed (row1 in flight)

    // init: C = M0 (element-wise from fp32 row in B0; pad reads garbage-safe)
    float4v acc[2][2];
#pragma unroll
    for (int R = 0; R < 2; ++R)
#pragma unroll
        for (int Cc = 0; Cc < 2; ++Cc)
#pragma unroll
            for (int i = 0; i < 4; ++i)
                acc[R][Cc][i] = B0[(16 * R + 4 * quad + i) * D + 16 * Cc + c];
    __builtin_amdgcn_s_waitcnt(0xC07F);  // drain init reads before B0 reuse

#pragma unroll 1
    for (int j = 1; j < CH; ++j) {
        const int jn = (j + 1 < CH) ? (j + 1) : j;
        float* nB = (j & 1) ? B0 : B1;   // buffer for row j+1
        float* cB = (j & 1) ? B1 : B0;   // buffer holding row j
        dma_row(table + (size_t)jl[jn] * EMB, nB, lane);

        // publish C row-major into CT
#pragma unroll
        for (int R = 0; R < 2; ++R)
#pragma unroll
            for (int Cc = 0; Cc < 2; ++Cc)
#pragma unroll
                for (int i = 0; i < 4; ++i)
                    CTw[(16 * R + 4 * quad + i) * CTW + 16 * Cc + c] = acc[R][Cc][i];

        __builtin_amdgcn_sched_barrier(0);
        __builtin_amdgcn_s_waitcnt(0x0074);  // vmcnt(4) lgkmcnt(0)
        __builtin_amdgcn_sched_barrier(0);

        // A-frags from CT: lane m=16R+c, k=8*quad+j' (8 consecutive floats)
        bf16x8 Ah[2], Al[2];
#pragma unroll
        for (int R = 0; R < 2; ++R) {
            const float* ap = CTw + (16 * R + c) * CTW + 8 * quad;
            float4v x0 = *(const float4v*)ap;
            float4v x1 = *(const float4v*)(ap + 4);
            if (q3) x1 = float4v{0.f, 0.f, 0.f, 0.f};  // k=28..31 -> 0
            float x[8] = {x0.x, x0.y, x0.z, x0.w, x1.x, x1.y, x1.z, x1.w};
            split_frags(x, Ah[R], Al[R]);
        }

        // B-frags from fp32 row (stride 28): lane n=16Cc+c, k=8*quad+t
        bf16x8 Bh[2], Bl[2];
#pragma unroll
        for (int Cc = 0; Cc < 2; ++Cc) {
            const float* bp = cB + (8 * quad) * D + 16 * Cc + c;
            float x[8];
#pragma unroll
            for (int t = 0; t < 8; ++t) x[t] = bp[t * D];
            if (q3) { x[4] = 0.f; x[5] = 0.f; x[6] = 0.f; x[7] = 0.f; }
            split_frags(x, Bh[Cc], Bl[Cc]);
        }

        // C_new = C * Mj  (hi*hi + hi*lo + lo*hi)
#pragma unroll
        for (int R = 0; R < 2; ++R)
#pragma unroll
            for (int Cc = 0; Cc < 2; ++Cc) {
                float4v d = {0.f, 0.f, 0.f, 0.f};
                d = __builtin_amdgcn_mfma_f32_16x16x32_bf16(Ah[R], Bh[Cc], d, 0, 0, 0);
                d = __builtin_amdgcn_mfma_f32_16x16x32_bf16(Ah[R], Bl[Cc], d, 0, 0, 0);
                d = __builtin_amdgcn_mfma_f32_16x16x32_bf16(Al[R], Bh[Cc], d, 0, 0, 0);
                acc[R][Cc] = d;
            }
    }

    // store rows/cols < 28 to ws partial (fp32 row-major 784)
    float* orow = ws0 + (size_t)w * EMB;
#pragma unroll
    for (int R = 0; R < 2; ++R)
#pragma unroll
        for (int Cc = 0; Cc < 2; ++Cc)
#pragma unroll
            for (int i = 0; i < 4; ++i) {
                const int row = 16 * R + 4 * quad + i;
                const int col = 16 * Cc + c;
                if (row < D && col < D) orow[row * D + col] = acc[R][Cc][i];
            }
}

// ================= fp32 vector engine (top + fallback, from R5) =================
__device__ __forceinline__ void xpose_write(const float4v ct[4],
                                            float* __restrict__ LTw,
                                            int it, int jt)
{
#pragma unroll
    for (int cc = 0; cc < 4; ++cc) {
        float4v t;
        t.x = ct[0][cc]; t.y = ct[1][cc]; t.z = ct[2][cc]; t.w = ct[3][cc];
        *(float4v*)&LTw[(4 * jt + cc) * D + 4 * it] = t;
    }
}

template <int CNT, typename F>
__device__ __forceinline__ void mat_chain(F rowptr, float* __restrict__ LTw,
                                          float* __restrict__ B0,
                                          float* __restrict__ B1,
                                          float4v ct[4], int it, int jt, int lane)
{
    dma_row(rowptr(1), B1, lane);

#pragma unroll 1
    for (int j = 1; j < CNT; ++j) {
        const int jn = (j + 1 < CNT) ? (j + 1) : j;
        float* nB = (j & 1) ? B0 : B1;
        float* cB = (j & 1) ? B1 : B0;
        dma_row(rowptr(jn), nB, lane);

        xpose_write(ct, LTw, it, jt);

        __builtin_amdgcn_sched_barrier(0);
        __builtin_amdgcn_s_waitcnt(0x0074);  // vmcnt(4) lgkmcnt(0)
        __builtin_amdgcn_sched_barrier(0);

        const float* ap = LTw + 4 * it;
        const float* bp = cB + 4 * jt;
        float4v acc[4] = {};
#pragma unroll
        for (int k = 0; k < 28; ++k) {
            float4v av = *(const float4v*)(ap + k * D);
            float4v bb = *(const float4v*)(bp + k * D);
#pragma unroll
            for (int r = 0; r < 4; ++r) acc[r] += bb * av[r];
        }
#pragma unroll
        for (int r = 0; r < 4; ++r) ct[r] = acc[r];
    }
}

__global__ __launch_bounds__(64, 1) void w2m_top(
    const float* __restrict__ ws0,
    float* __restrict__ out)
{
    __shared__ float LT[EMB] __attribute__((aligned(16)));
    __shared__ float BBt[2 * BUFF] __attribute__((aligned(16)));
    const int lane = threadIdx.x;
    const int b = blockIdx.x;
    int it = lane / 7, jt = lane % 7;
    const bool act = lane < 49;
    if (!act) { it = 6; jt = 6; }

    const float* base = ws0 + (size_t)b * CH * EMB;
    float4v ct[4];
#pragma unroll
    for (int r = 0; r < 4; ++r)
        ct[r] = *(const float4v*)(base + (4 * it + r) * D + 4 * jt);

    mat_chain<CH>([&](int j) { return base + (size_t)j * EMB; },
                  LT, &BBt[0], &BBt[BUFF], ct, it, jt, lane);

    if (act) {
        float* orow = out + (size_t)b * EMB;
#pragma unroll
        for (int r = 0; r < 4; ++r)
            *(float4v*)(orow + (4 * it + r) * D + 4 * jt) = ct[r];
    }
}

__global__ __launch_bounds__(64, 1) void w2m_serial(
    const int* __restrict__ sent,
    const float* __restrict__ table,
    float* __restrict__ out)
{
    __shared__ float LT[EMB] __attribute__((aligned(16)));
    __shared__ float BBs[2 * BUFF] __attribute__((aligned(16)));
    const int lane = threadIdx.x;
    const int b = blockIdx.x;
    int it = lane / 7, jt = lane % 7;
    const bool act = lane < 49;
    if (!act) { it = 6; jt = 6; }

    const int myidx = sent[b * SEQ + lane];
    int jls[SEQ];
#pragma unroll
    for (int s = 0; s < SEQ; ++s) jls[s] = __builtin_amdgcn_readlane(myidx, s);

    const float* row0 = table + (size_t)jls[0] * EMB;
    float4v ct[4];
#pragma unroll
    for (int r = 0; r < 4; ++r)
        ct[r] = *(const float4v*)(row0 + (4 * it + r) * D + 4 * jt);

    mat_chain<SEQ>([&](int s) { return table + (size_t)jls[s] * EMB; },
                   LT, &BBs[0], &BBs[BUFF], ct, it, jt, lane);

    if (act) {
        float* orow = out + (size_t)b * EMB;
#pragma unroll
        for (int r = 0; r < 4; ++r)
            *(float4v*)(orow + (4 * it + r) * D + 4 * jt) = ct[r];
    }
}

extern "C" void kernel_launch(void* const* d_in, const int* in_sizes, int n_in,
                              void* d_out, int out_size, void* d_ws, size_t ws_size,
                              hipStream_t stream) {
    const int* sent = (const int*)d_in[0];
    const float* table = (const float*)d_in[1];
    float* out = (float*)d_out;
    const int batch = in_sizes[0] / SEQ;                  // 1024
    const size_t ws_needed = (size_t)batch * CH * EMB * sizeof(float);  // 25.7 MB

    if (ws_size >= ws_needed) {
        float* ws0 = (float*)d_ws;
        const int waves1 = batch * CH;                    // 8192 leaf waves
        hipLaunchKernelGGL(w2m_leaf_mfma, dim3(waves1 / 4), dim3(256), 0, stream,
                           sent, table, ws0);
        hipLaunchKernelGGL(w2m_top, dim3(batch), dim3(64), 0, stream,
                           ws0, out);
    } else {
        hipLaunchKernelGGL(w2m_serial, dim3(batch), dim3(64), 0, stream,
                           sent, table, out);
    }
}

// Round 7
// 163.553 us; speedup vs baseline: 1.4311x; 1.0378x over previous
//
#include <hip/hip_runtime.h>
#include <stdint.h>

#define SEQ 64
#define D 28
#define EMB 784   // 28*28
#define CH 8      // leaf chain length
#define BUFF 832  // B-buffer floats: 3328 B = exact DMA coverage (3*1024+256)
#define CTW 36    // CT row stride floats (16B-aligned b128 reads, 2-way-free banks)
#define CTSZ (32 * CTW)  // 1152 floats per wave

typedef float float4v __attribute__((ext_vector_type(4)));
typedef __bf16 bf16x8 __attribute__((ext_vector_type(8)));

union FragU { unsigned u[4]; bf16x8 v; };

__device__ __forceinline__ unsigned fbits(float x) { union { float f; unsigned u; } t; t.f = x; return t.u; }
__device__ __forceinline__ float fof(unsigned u) { union { unsigned u; float f; } t; t.u = u; return t.f; }

// Split 8 fp32 (k-order) into hi/lo bf16 fragments (truncation split:
// x = hi + lo + O(2^-16 |x|); MFMA computes hi*hi + hi*lo + lo*hi).
__device__ __forceinline__ void split_frags(const float x[8], bf16x8& hi, bf16x8& lo)
{
    FragU H, L;
#pragma unroll
    for (int p = 0; p < 4; ++p) {
        unsigned ua = fbits(x[2 * p]), ub = fbits(x[2 * p + 1]);
        H.u[p] = (ua >> 16) | (ub & 0xFFFF0000u);
        unsigned la = fbits(x[2 * p]     - fof(ua & 0xFFFF0000u));
        unsigned lb = fbits(x[2 * p + 1] - fof(ub & 0xFFFF0000u));
        L.u[p] = (la >> 16) | (lb & 0xFFFF0000u);
    }
    hi = H.v; lo = L.v;
}

// ---- async global->LDS DMA of one 3136 B row (+192 B tail overread, which
// stays inside the source allocation and lands in LDS bytes [3136,3328) of
// the 3328 B buffer — never read as data).
__device__ __forceinline__ void dma_row(const float* grow, float* lbuf, int lane)
{
    const char* g16 = (const char*)grow + lane * 16;
    const char* g4  = (const char*)grow + 3072 + lane * 4;
    char* l = (char*)lbuf;
    __builtin_amdgcn_global_load_lds((const __attribute__((address_space(1))) void*)(g16),
                                     (__attribute__((address_space(3))) void*)(l), 16, 0, 0);
    __builtin_amdgcn_global_load_lds((const __attribute__((address_space(1))) void*)(g16 + 1024),
                                     (__attribute__((address_space(3))) void*)(l + 1024), 16, 0, 0);
    __builtin_amdgcn_global_load_lds((const __attribute__((address_space(1))) void*)(g16 + 2048),
                                     (__attribute__((address_space(3))) void*)(l + 2048), 16, 0, 0);
    __builtin_amdgcn_global_load_lds((const __attribute__((address_space(1))) void*)(g4),
                                     (__attribute__((address_space(3))) void*)(l + 3072), 4, 0, 0);
}

// ================= shared MFMA chain engine =================
// acc = M_{row 0}; then acc <- acc * M_{rowptr(j)} for j=1..CNT-1.
// State C in 2x2 16x16 D-frags (C/D layout: col=lane&15, row=(lane>>4)*4+reg).
// Per step: publish C row-major to CT (stride 36), A-frags from CT (b128),
// B-frags from the DMA'd fp32 row (strided b32), 12 MFMAs (hi/lo split).
// k>=28 zeroed in registers; pad rows/cols only ever flow to pad rows/cols.
template <int CNT, typename F>
__device__ __forceinline__ void mfma_chain(F rowptr,
                                           float* __restrict__ CTw,
                                           float* __restrict__ B0,
                                           float* __restrict__ B1,
                                           float4v acc[2][2],
                                           int lane)
{
    const int c = lane & 15;
    const int quad = lane >> 4;
    const bool q3 = (quad == 3);

    dma_row(rowptr(0), B0, lane);
    dma_row(rowptr(1), B1, lane);
    __builtin_amdgcn_s_waitcnt(0x0074);  // vmcnt(4): row0 landed, row1 in flight

    // init: acc = M0 element-wise from B0. Clamped indices keep reads inside
    // the 832-float buffer; pad rows/cols duplicate row/col 27 (flows to pad).
#pragma unroll
    for (int R = 0; R < 2; ++R)
#pragma unroll
        for (int Cc = 0; Cc < 2; ++Cc)
#pragma unroll
            for (int i = 0; i < 4; ++i) {
                const int rr = 16 * R + 4 * quad + i;
                const int cc = 16 * Cc + c;
                acc[R][Cc][i] = B0[(rr < D ? rr : D - 1) * D + (cc < D ? cc : D - 1)];
            }
    __builtin_amdgcn_s_waitcnt(0xC07F);  // drain init reads before B0 reuse

#pragma unroll 1
    for (int j = 1; j < CNT; ++j) {
        const int jn = (j + 1 < CNT) ? (j + 1) : j;
        float* nB = (j & 1) ? B0 : B1;   // buffer for row j+1
        float* cB = (j & 1) ? B1 : B0;   // buffer holding row j
        dma_row(rowptr(jn), nB, lane);

        // publish C row-major into CT (banks: 2-way aliasing only -> free)
#pragma unroll
        for (int R = 0; R < 2; ++R)
#pragma unroll
            for (int Cc = 0; Cc < 2; ++Cc)
#pragma unroll
                for (int i = 0; i < 4; ++i)
                    CTw[(16 * R + 4 * quad + i) * CTW + 16 * Cc + c] = acc[R][Cc][i];

        __builtin_amdgcn_sched_barrier(0);
        __builtin_amdgcn_s_waitcnt(0x0074);  // vmcnt(4) lgkmcnt(0)
        __builtin_amdgcn_sched_barrier(0);

        // A-frags from CT: lane m=16R+c, k=8*quad+j'
        bf16x8 Ah[2], Al[2];
#pragma unroll
        for (int R = 0; R < 2; ++R) {
            const float* ap = CTw + (16 * R + c) * CTW + 8 * quad;
            float4v x0 = *(const float4v*)ap;
            float4v x1 = *(const float4v*)(ap + 4);
            if (q3) x1 = float4v{0.f, 0.f, 0.f, 0.f};  // k=28..31 -> 0
            float x[8] = {x0.x, x0.y, x0.z, x0.w, x1.x, x1.y, x1.z, x1.w};
            split_frags(x, Ah[R], Al[R]);
        }

        // B-frags from fp32 row (stride 28): lane n=16Cc+c, k=8*quad+t
        bf16x8 Bh[2], Bl[2];
#pragma unroll
        for (int Cc = 0; Cc < 2; ++Cc) {
            const float* bp = cB + (8 * quad) * D + 16 * Cc + c;
            float x[8];
#pragma unroll
            for (int t = 0; t < 8; ++t) x[t] = bp[t * D];
            if (q3) { x[4] = 0.f; x[5] = 0.f; x[6] = 0.f; x[7] = 0.f; }
            split_frags(x, Bh[Cc], Bl[Cc]);
        }

        // C_new = C * Mj  (hi*hi + hi*lo + lo*hi)
#pragma unroll
        for (int R = 0; R < 2; ++R)
#pragma unroll
            for (int Cc = 0; Cc < 2; ++Cc) {
                float4v d = {0.f, 0.f, 0.f, 0.f};
                d = __builtin_amdgcn_mfma_f32_16x16x32_bf16(Ah[R], Bh[Cc], d, 0, 0, 0);
                d = __builtin_amdgcn_mfma_f32_16x16x32_bf16(Ah[R], Bl[Cc], d, 0, 0, 0);
                d = __builtin_amdgcn_mfma_f32_16x16x32_bf16(Al[R], Bh[Cc], d, 0, 0, 0);
                acc[R][Cc] = d;
            }
    }
}

// Store rows/cols < 28 of the D-frag accumulator to a row-major 784 buffer.
__device__ __forceinline__ void store_acc(const float4v acc[2][2],
                                          float* __restrict__ orow, int lane)
{
    const int c = lane & 15;
    const int quad = lane >> 4;
#pragma unroll
    for (int R = 0; R < 2; ++R)
#pragma unroll
        for (int Cc = 0; Cc < 2; ++Cc)
#pragma unroll
            for (int i = 0; i < 4; ++i) {
                const int row = 16 * R + 4 * quad + i;
                const int col = 16 * Cc + c;
                if (row < D && col < D) orow[row * D + col] = acc[R][Cc][i];
            }
}

// Leaf: wave w = (sentence b, group g) computes product of words 8g..8g+7.
// 128-thread blocks (2 waves): 22528 B LDS -> 7 blocks/CU = 14 waves/CU.
__global__ __launch_bounds__(128, 1) void w2m_leaf_mfma(
    const int* __restrict__ sent,
    const float* __restrict__ table,
    float* __restrict__ ws0)
{
    __shared__ float CT[2 * CTSZ] __attribute__((aligned(16)));
    __shared__ float BB[2 * 2 * BUFF] __attribute__((aligned(16)));
    const int lane = threadIdx.x & 63;
    const int wid  = threadIdx.x >> 6;
    const int w = blockIdx.x * 2 + wid;   // 0..8191
    const int b = w >> 3;
    const int g = w & 7;
    float* CTw = &CT[wid * CTSZ];
    float* B0 = &BB[wid * 2 * BUFF];
    float* B1 = B0 + BUFF;

    const int myidx = sent[b * SEQ + 8 * g + (lane & 7)];
    int jl[CH];
#pragma unroll
    for (int j = 0; j < CH; ++j) jl[j] = __builtin_amdgcn_readlane(myidx, j);

    float4v acc[2][2];
    mfma_chain<CH>([&](int j) { return table + (size_t)jl[j] * EMB; },
                   CTw, B0, B1, acc, lane);

    store_acc(acc, ws0 + (size_t)w * EMB, lane);
}

// Top: wave b multiplies the 8 partial products of sentence b -> d_out.
__global__ __launch_bounds__(128, 1) void w2m_top_mfma(
    const float* __restrict__ ws0,
    float* __restrict__ out)
{
    __shared__ float CT[2 * CTSZ] __attribute__((aligned(16)));
    __shared__ float BB[2 * 2 * BUFF] __attribute__((aligned(16)));
    const int lane = threadIdx.x & 63;
    const int wid  = threadIdx.x >> 6;
    const int b = blockIdx.x * 2 + wid;   // 0..1023
    float* CTw = &CT[wid * CTSZ];
    float* B0 = &BB[wid * 2 * BUFF];
    float* B1 = B0 + BUFF;

    const float* base = ws0 + (size_t)b * CH * EMB;
    float4v acc[2][2];
    mfma_chain<CH>([&](int j) { return base + (size_t)j * EMB; },
                   CTw, B0, B1, acc, lane);

    store_acc(acc, out + (size_t)b * EMB, lane);
}

// ================= fp32 serial fallback (ws too small; from R5) ============
__device__ __forceinline__ void xpose_write(const float4v ct[4],
                                            float* __restrict__ LTw,
                                            int it, int jt)
{
#pragma unroll
    for (int cc = 0; cc < 4; ++cc) {
        float4v t;
        t.x = ct[0][cc]; t.y = ct[1][cc]; t.z = ct[2][cc]; t.w = ct[3][cc];
        *(float4v*)&LTw[(4 * jt + cc) * D + 4 * it] = t;
    }
}

__global__ __launch_bounds__(64, 1) void w2m_serial(
    const int* __restrict__ sent,
    const float* __restrict__ table,
    float* __restrict__ out)
{
    __shared__ float LT[EMB] __attribute__((aligned(16)));
    __shared__ float BBs[2 * BUFF] __attribute__((aligned(16)));
    const int lane = threadIdx.x;
    const int b = blockIdx.x;
    int it = lane / 7, jt = lane % 7;
    const bool act = lane < 49;
    if (!act) { it = 6; jt = 6; }

    const int myidx = sent[b * SEQ + lane];
    int jls[SEQ];
#pragma unroll
    for (int s = 0; s < SEQ; ++s) jls[s] = __builtin_amdgcn_readlane(myidx, s);

    const float* row0 = table + (size_t)jls[0] * EMB;
    float4v ct[4];
#pragma unroll
    for (int r = 0; r < 4; ++r)
        ct[r] = *(const float4v*)(row0 + (4 * it + r) * D + 4 * jt);

    float* Bs0 = &BBs[0];
    float* Bs1 = &BBs[BUFF];
    dma_row(table + (size_t)jls[1] * EMB, Bs1, lane);

#pragma unroll 1
    for (int j = 1; j < SEQ; ++j) {
        const int jn = (j + 1 < SEQ) ? (j + 1) : j;
        float* nB = (j & 1) ? Bs0 : Bs1;
        float* cB = (j & 1) ? Bs1 : Bs0;
        dma_row(table + (size_t)jls[jn] * EMB, nB, lane);

        xpose_write(ct, LT, it, jt);

        __builtin_amdgcn_sched_barrier(0);
        __builtin_amdgcn_s_waitcnt(0x0074);  // vmcnt(4) lgkmcnt(0)
        __builtin_amdgcn_sched_barrier(0);

        const float* ap = LT + 4 * it;
        const float* bp = cB + 4 * jt;
        float4v acc[4] = {};
#pragma unroll
        for (int k = 0; k < 28; ++k) {
            float4v av = *(const float4v*)(ap + k * D);
            float4v bb = *(const float4v*)(bp + k * D);
#pragma unroll
            for (int r = 0; r < 4; ++r) acc[r] += bb * av[r];
        }
#pragma unroll
        for (int r = 0; r < 4; ++r) ct[r] = acc[r];
    }

    if (act) {
        float* orow = out + (size_t)b * EMB;
#pragma unroll
        for (int r = 0; r < 4; ++r)
            *(float4v*)(orow + (4 * it + r) * D + 4 * jt) = ct[r];
    }
}

extern "C" void kernel_launch(void* const* d_in, const int* in_sizes, int n_in,
                              void* d_out, int out_size, void* d_ws, size_t ws_size,
                              hipStream_t stream) {
    const int* sent = (const int*)d_in[0];
    const float* table = (const float*)d_in[1];
    float* out = (float*)d_out;
    const int batch = in_sizes[0] / SEQ;                  // 1024
    const size_t ws_needed = (size_t)batch * CH * EMB * sizeof(float);  // 25.7 MB

    if (ws_size >= ws_needed) {
        float* ws0 = (float*)d_ws;
        const int waves1 = batch * CH;                    // 8192 leaf waves
        hipLaunchKernelGGL(w2m_leaf_mfma, dim3(waves1 / 2), dim3(128), 0, stream,
                           sent, table, ws0);
        hipLaunchKernelGGL(w2m_top_mfma, dim3(batch / 2), dim3(128), 0, stream,
                           ws0, out);
    } else {
        hipLaunchKernelGGL(w2m_serial, dim3(batch), dim3(64), 0, stream,
                           sent, table, out);
    }
}